// Round 8
// baseline (185.838 us; speedup 1.0000x reference)
//
#include <hip/hip_runtime.h>

typedef unsigned short u16;
typedef unsigned int u32;
typedef unsigned long long u64;
typedef __attribute__((ext_vector_type(8))) short bf16x8;   // 8 bf16 = 4 VGPRs
typedef __attribute__((ext_vector_type(4))) float f32x4;
typedef __attribute__((ext_vector_type(2))) float f32x2;
typedef __attribute__((ext_vector_type(2))) unsigned int u32x2;
typedef __attribute__((ext_vector_type(4))) unsigned int u32x4;

#define MFMA16(A, B, C) __builtin_amdgcn_mfma_f32_16x16x32_bf16(A, B, C, 0, 0, 0)

__device__ __forceinline__ u16 f2bf(float f) {
  union { float f; unsigned u; } x; x.f = f;
  unsigned r = x.u + 0x7fffu + ((x.u >> 16) & 1u);   // RNE
  return (u16)(r >> 16);
}

// pack two fp32 -> two bf16 in one dword via HW cvt_pk (RNE): lo16=a, hi16=b.
__device__ __forceinline__ u32 pack_bf2(float a, float b) {
  u32 r;
  asm("v_cvt_pk_bf16_f32 %0, %1, %2" : "=v"(r) : "v"(a), "v"(b));
  return r;
}

// packed fp32 math (VOP3P, MI200+): d = a*b+c / a+b per 32-bit half
__device__ __forceinline__ f32x2 pk_fma(f32x2 a, f32x2 b, f32x2 c) {
  f32x2 d;
  asm("v_pk_fma_f32 %0, %1, %2, %3" : "=v"(d) : "v"(a), "v"(b), "v"(c));
  return d;
}
__device__ __forceinline__ f32x2 pk_add(f32x2 a, f32x2 b) {
  f32x2 d;
  asm("v_pk_add_f32 %0, %1, %2" : "=v"(d) : "v"(a), "v"(b));
  return d;
}

// async global->LDS, 16B/lane; dest must be wave-uniform base + lane*16
__device__ __forceinline__ void gload_lds16(const u16* g, u16* l) {
  __builtin_amdgcn_global_load_lds((const __attribute__((address_space(1))) void*)g,
                                   (__attribute__((address_space(3))) void*)l,
                                   16, 0, 0);
}

// ---------------------------------------------------------------------------
// fp32 -> bf16 for x, Wq|Wk|Wv (concat -> Wqkvb), Wo; last block builds the
// per-key bias table Mb[key] = K3 + (mask ? -1e6 : 0)  (log2-domain).
// ---------------------------------------------------------------------------
__global__ __launch_bounds__(256) void cvt_all(const float* __restrict__ x,
                                               const float* __restrict__ Wq,
                                               const float* __restrict__ Wk,
                                               const float* __restrict__ Wv,
                                               const float* __restrict__ Wo,
                                               const int* __restrict__ mask,
                                               u16* __restrict__ xb,
                                               u16* __restrict__ Wqkvb,
                                               u16* __restrict__ Wob,
                                               float* __restrict__ Mbg,
                                               int NE, int NW, int NB) {
  if ((int)blockIdx.x == NB) {              // bias-table block: 4096 keys
    const int t = threadIdx.x;
    const int j0 = t * 16;
    const float K3C = -8.0f * 1.44269504f;
    const float KMS = K3C - 1.0e6f;         // exp2 -> exactly 0
#pragma unroll
    for (int jj = 0; jj < 16; jj += 4) {
      const int4 m4 = *(const int4*)(mask + j0 + jj);
      float4 o;
      o.x = m4.x ? KMS : K3C;
      o.y = m4.y ? KMS : K3C;
      o.z = m4.z ? KMS : K3C;
      o.w = m4.w ? KMS : K3C;
      *(float4*)(Mbg + j0 + jj) = o;
    }
    return;
  }
  const int e = (blockIdx.x * 256 + threadIdx.x) * 8;
  const float* s;
  u16* d;
  if (e < NE) { s = x + e; d = xb + e; }
  else {
    int f = e - NE;
    if (f < 3 * NW) {
      d = Wqkvb + f;
      s = (f < NW) ? Wq + f : (f < 2 * NW) ? Wk + (f - NW) : Wv + (f - 2 * NW);
    } else { f -= 3 * NW; s = Wo + f; d = Wob + f; }
  }
  const float4 a = *(const float4*)s;
  const float4 b = *(const float4*)(s + 4);
  bf16x8 o;
  o[0] = (short)f2bf(a.x); o[1] = (short)f2bf(a.y);
  o[2] = (short)f2bf(a.z); o[3] = (short)f2bf(a.w);
  o[4] = (short)f2bf(b.x); o[5] = (short)f2bf(b.y);
  o[6] = (short)f2bf(b.z); o[7] = (short)f2bf(b.w);
  *(bf16x8*)d = o;
}

// ---------------------------------------------------------------------------
// Fused QKV NT GEMM: [4096,1024] @ [3072,1024]^T. 128x128 tile, BK=64,
// global_load_lds x16 staging, XOR-chunk swizzle, XCD-chunked block order.
// V -> per-head-transposed Vt with key interleave matching attn's in-register
// P fragments: p = r + 4*(T&1) + 8*quad + 32*(T>>1) for key k = T*16+quad*4+r.
// ---------------------------------------------------------------------------
__global__ __launch_bounds__(256) void gemm_qkv(const u16* __restrict__ A,
                                                const u16* __restrict__ B,
                                                u16* __restrict__ Qo,
                                                u16* __restrict__ Ko,
                                                u16* __restrict__ Vto,
                                                int M, int N, int K) {
  __shared__ alignas(16) u16 As[128 * 64];   // 16 KB, chunk-linear + XOR col
  __shared__ alignas(16) u16 Bs[128 * 64];   // 16 KB
  const int t = threadIdx.x;
  const int lane = t & 63, wave = t >> 6;
  const int quad = lane >> 4, l16 = lane & 15;
  // XCD-chunked swizzle: 768 blocks = 8 XCDs x 96 (bijective).
  const int bid = blockIdx.x;
  const int swz = (bid & 7) * 96 + (bid >> 3);
  const int m0 = (swz / 24) * 128, n0 = (swz % 24) * 128;
  const int wm = (wave >> 1) * 64, wn = (wave & 1) * 64;
  const int sx = l16 & 7;

  f32x4 acc[4][4] = {};

  for (int kk = 0; kk < K; kk += 64) {
#pragma unroll
    for (int i = 0; i < 4; i++) {
      const int c = t + i * 256;              // chunk id in [0,1024)
      const int row = c >> 3, sub = c & 7;
      const int col = ((sub ^ (row & 7)) * 8);
      gload_lds16(A + (size_t)(m0 + row) * K + kk + col, As + (size_t)c * 8);
      gload_lds16(B + (size_t)(n0 + row) * K + kk + col, Bs + (size_t)c * 8);
    }
    __syncthreads();

#pragma unroll
    for (int ks = 0; ks < 2; ks++) {
      bf16x8 af[4], bfr[4];
#pragma unroll
      for (int i = 0; i < 4; i++)
        af[i] = *(const bf16x8*)(As + (wm + i * 16 + l16) * 64 +
                                 ((ks * 4 + quad) ^ sx) * 8);
#pragma unroll
      for (int j = 0; j < 4; j++)
        bfr[j] = *(const bf16x8*)(Bs + (wn + j * 16 + l16) * 64 +
                                  ((ks * 4 + quad) ^ sx) * 8);
#pragma unroll
      for (int i = 0; i < 4; i++)
#pragma unroll
        for (int j = 0; j < 4; j++)
          acc[i][j] = MFMA16(af[i], bfr[j], acc[i][j]);
    }
    __syncthreads();
  }

  const int G = ((m0 + wm) & 2047) >> 6;
#pragma unroll
  for (int j = 0; j < 4; j++) {
    const int col = n0 + wn + j * 16 + l16;
    if (col < 1024) {
#pragma unroll
      for (int i = 0; i < 4; i++)
#pragma unroll
        for (int r = 0; r < 4; r++)
          Qo[(size_t)(m0 + wm + i * 16 + quad * 4 + r) * 1024 + col] =
              f2bf(acc[i][j][r]);
    } else if (col < 2048) {
#pragma unroll
      for (int i = 0; i < 4; i++)
#pragma unroll
        for (int r = 0; r < 4; r++)
          Ko[(size_t)(m0 + wm + i * 16 + quad * 4 + r) * 1024 + (col - 1024)] =
              f2bf(acc[i][j][r]);
    } else {
      u16* base = Vto + ((size_t)(m0 >> 11) * 1024 + (col - 2048)) * 2048 + G * 64;
      const int C = 8 * (quad & 1) + 16 * (quad >> 1);
      u32x4 w0, w1;
      w0.x = pack_bf2(acc[0][j][0], acc[0][j][1]);
      w0.y = pack_bf2(acc[0][j][2], acc[0][j][3]);
      w0.z = pack_bf2(acc[1][j][0], acc[1][j][1]);
      w0.w = pack_bf2(acc[1][j][2], acc[1][j][3]);
      w1.x = pack_bf2(acc[2][j][0], acc[2][j][1]);
      w1.y = pack_bf2(acc[2][j][2], acc[2][j][3]);
      w1.z = pack_bf2(acc[3][j][0], acc[3][j][1]);
      w1.w = pack_bf2(acc[3][j][2], acc[3][j][3]);
      *(u32x4*)(base + C) = w0;
      *(u32x4*)(base + C + 32) = w1;
    }
  }
}

// ---------------------------------------------------------------------------
// Out GEMM (unfused, DMA-staged): C[4096,1024] fp32 = Ao @ Wo^T.
// ---------------------------------------------------------------------------
__global__ __launch_bounds__(256) void gemm_out(const u16* __restrict__ A,
                                                const u16* __restrict__ B,
                                                float* __restrict__ C,
                                                int M, int N, int K) {
  __shared__ alignas(16) u16 As[128 * 64];   // 16 KB
  __shared__ alignas(16) u16 Bs[64 * 64];    // 8 KB
  const int t = threadIdx.x;
  const int lane = t & 63, wave = t >> 6;
  const int quad = lane >> 4, l16 = lane & 15;
  // XCD-chunked swizzle: 512 blocks = 8 x 64 (bijective).
  const int bid = blockIdx.x;
  const int swz = (bid & 7) * 64 + (bid >> 3);
  const int m0 = (swz >> 4) * 128, n0 = (swz & 15) * 64;
  const int wm = (wave >> 1) * 64, wn = (wave & 1) * 32;
  const int sx = l16 & 7;

  f32x4 acc[4][2] = {};

  for (int kk = 0; kk < K; kk += 64) {
#pragma unroll
    for (int i = 0; i < 4; i++) {
      const int c = t + i * 256;              // A chunks [0,1024)
      const int row = c >> 3, sub = c & 7;
      gload_lds16(A + (size_t)(m0 + row) * K + kk + ((sub ^ (row & 7)) * 8),
                  As + (size_t)c * 8);
    }
#pragma unroll
    for (int i = 0; i < 2; i++) {
      const int c = t + i * 256;              // B chunks [0,512)
      const int row = c >> 3, sub = c & 7;
      gload_lds16(B + (size_t)(n0 + row) * K + kk + ((sub ^ (row & 7)) * 8),
                  Bs + (size_t)c * 8);
    }
    __syncthreads();

#pragma unroll
    for (int ks = 0; ks < 2; ks++) {
      bf16x8 af[4], bfr[2];
#pragma unroll
      for (int i = 0; i < 4; i++)
        af[i] = *(const bf16x8*)(As + (wm + i * 16 + l16) * 64 +
                                 ((ks * 4 + quad) ^ sx) * 8);
#pragma unroll
      for (int j = 0; j < 2; j++)
        bfr[j] = *(const bf16x8*)(Bs + (wn + j * 16 + l16) * 64 +
                                  ((ks * 4 + quad) ^ sx) * 8);
#pragma unroll
      for (int i = 0; i < 4; i++)
#pragma unroll
        for (int j = 0; j < 2; j++)
          acc[i][j] = MFMA16(af[i], bfr[j], acc[i][j]);
    }
    __syncthreads();
  }

#pragma unroll
  for (int i = 0; i < 4; i++)
#pragma unroll
    for (int j = 0; j < 2; j++)
#pragma unroll
      for (int r = 0; r < 4; r++)
        C[(size_t)(m0 + wm + i * 16 + quad * 4 + r) * N + n0 + wn + j * 16 + l16] =
            acc[i][j][r];
}

// ---------------------------------------------------------------------------
// Flash attention v13: softmax VALU diet via sign-split separable bias.
// fe = k+q-2047 has uniform sign per (tile,wave) except when kq=kc+q0 in
// (1969,2047) -- at most 2 of 32 tiles. Uniform-sign tiles: -K2|fe| folds
// into per-key LDS tables Msp/Msm = Mb -/+ K2*(k-2047) plus a per-lane
// constant cq -- hot path is ONE v_pk_fma + ONE v_pk_add per element pair.
// Straddle tiles: exact identity -K2|fe| = -K2*fe + 2K2*min(fe,0) on Msp.
// Structure (8 waves x 16 q, grid 512, dbuf staging) = passing v12.
// ---------------------------------------------------------------------------
__global__ __launch_bounds__(512) void attn_fwd(const u16* __restrict__ Q,
                                                const u16* __restrict__ Kb_,
                                                const u16* __restrict__ Vt,
                                                const float* __restrict__ Mb,
                                                u16* __restrict__ Ao) {
  constexpr int S = 2048, E = 1024;
  __shared__ alignas(16) u16 Ks[2][64 * 64];   // 16 KB
  __shared__ alignas(16) u16 Vs[2][64 * 64];   // 16 KB
  __shared__ alignas(16) float Msp[2048];      // 8 KB: Mb - K2*(k-2047)
  __shared__ alignas(16) float Msm[2048];      // 8 KB: Mb + K2*(k-2047)
  const int t = threadIdx.x;
  const int lane = t & 63, wave = t >> 6;      // 8 waves
  const int quad = lane >> 4, l16 = lane & 15;
  // XCD-chunked swizzle: 512 blocks = 8 x 64 (bijective).
  const int bid = blockIdx.x;
  const int swz = (bid & 7) * 64 + (bid >> 3);
  const int xq = swz & 15, bh = swz >> 4;
  const int b = bh >> 4, h = bh & 15;
  const int q0 = xq * 128 + wave * 16;         // 16 q-rows per wave

  const int kr0 = t >> 3;                      // chunk t in [0,512)
  const int kcol0 = ((t & 7) ^ (kr0 & 7)) * 8;
  const u16* kP0 = Kb_ + (size_t)(b * S + kr0) * E + h * 64 + kcol0;
  const u16* vbase = Vt + (size_t)(b * 16 + h) * 64 * S;
  const u16* vP0 = vbase + (size_t)kr0 * S + kcol0;

  bf16x8 aq[2];                        // Q fragments (B-operand after swap)
  {
    const u16* qp = Q + ((size_t)(b * S) + q0 + l16) * E + h * 64;
    aq[0] = *(const bf16x8*)(qp + quad * 8);
    aq[1] = *(const bf16x8*)(qp + 32 + quad * 8);
  }

  const int sx = l16 & 7;
  const float K1 = 0.125f * 1.44269504f;
  const float K2 = 2.44140625e-4f * 1.44269504f;

  float lr = 0.f;
  f32x4 accO[4] = {};

  gload_lds16(kP0, Ks[0] + t * 8);
  gload_lds16(vP0, Vs[0] + t * 8);
  // build sign-split bias tables (overlaps with K/V DMA)
  {
    const float4 m4 = *(const float4*)(Mb + b * 2048 + t * 4);
    const float kb = (float)(t * 4) - 2047.0f;
    float4 pp, mm;
    pp.x = fmaf(-K2, kb,       m4.x);  mm.x = fmaf(K2, kb,       m4.x);
    pp.y = fmaf(-K2, kb + 1.f, m4.y);  mm.y = fmaf(K2, kb + 1.f, m4.y);
    pp.z = fmaf(-K2, kb + 2.f, m4.z);  mm.z = fmaf(K2, kb + 2.f, m4.z);
    pp.w = fmaf(-K2, kb + 3.f, m4.w);  mm.w = fmaf(K2, kb + 3.f, m4.w);
    *(float4*)(Msp + t * 4) = pp;
    *(float4*)(Msm + t * 4) = mm;
  }
  __syncthreads();

  const float qn = (float)(q0 + l16);
  const float cqPs = -K2 * qn, cqMs = K2 * qn;
  const f32x2 K1p = {K1, K1};
  const f32x2 cqPp = {cqPs, cqPs}, cqMp = {cqMs, cqMs};
  const float fb0 = (float)(quad * 4 + q0 + l16 - 2047);
  const float twoK2 = 2.0f * K2;

  int buf = 0;
  for (int kc = 0; kc < 2048; kc += 64) {
    if (kc + 64 < 2048) {
      const int kn = kc + 64;
      gload_lds16(kP0 + (size_t)kn * E, Ks[buf ^ 1] + t * 8);
      gload_lds16(vP0 + kn, Vs[buf ^ 1] + t * 8);
    }
    const u16* ks = Ks[buf];
    const u16* vs = Vs[buf];

    bf16x8 bk[4][2];                 // K fragments (A-operand after swap)
#pragma unroll
    for (int T = 0; T < 4; T++)
#pragma unroll
      for (int dh = 0; dh < 2; dh++)
        bk[T][dh] = *(const bf16x8*)(ks + (T * 16 + l16) * 64 +
                                     ((dh * 4 + quad) ^ sx) * 8);

    // swapped QK^T: s[T][r] = S[key = kc+16T+quad*4+r][q = q0+l16]
    f32x4 s[4] = {};
#pragma unroll
    for (int T = 0; T < 4; T++) {
      s[T] = MFMA16(bk[T][0], aq[0], s[T]);
      s[T] = MFMA16(bk[T][1], aq[1], s[T]);
    }

    // softmax + in-register P fragment build
    const int kq = kc + q0;
    u32 pw[2][4];                    // [kst][dword]
    if (kq >= 2047 || kq <= 1969) {  // uniform-sign fast path (30/32 tiles)
      const float* mst = (kq >= 2047) ? Msp : Msm;
      const f32x2 cqp = (kq >= 2047) ? cqPp : cqMp;
#pragma unroll
      for (int T = 0; T < 4; T++) {
        const f32x4 m4v = *(const f32x4*)(mst + kc + 16 * T + quad * 4);
        const f32x2 s01 = {s[T][0], s[T][1]}, s23 = {s[T][2], s[T][3]};
        const f32x2 m01 = {m4v[0], m4v[1]}, m23 = {m4v[2], m4v[3]};
        const f32x2 a01 = pk_add(pk_fma(s01, K1p, m01), cqp);
        const f32x2 a23 = pk_add(pk_fma(s23, K1p, m23), cqp);
        const float p0 = __builtin_amdgcn_exp2f(a01[0]);
        const float p1 = __builtin_amdgcn_exp2f(a01[1]);
        const float p2 = __builtin_amdgcn_exp2f(a23[0]);
        const float p3 = __builtin_amdgcn_exp2f(a23[1]);
        lr += (p0 + p1) + (p2 + p3);
        pw[T >> 1][(T & 1) * 2 + 0] = pack_bf2(p0, p1);
        pw[T >> 1][(T & 1) * 2 + 1] = pack_bf2(p2, p3);
      }
    } else {                         // straddle (<=2 tiles): exact correction
      const float fbLk = fb0 + (float)kc;
#pragma unroll
      for (int T = 0; T < 4; T++) {
        const f32x4 m4v = *(const f32x4*)(Msp + kc + 16 * T + quad * 4);
        float p[4];
#pragma unroll
        for (int r = 0; r < 4; r++) {
          const float fe = fbLk + (float)(16 * T + r);
          const float tv = fmaf(s[T][r], K1, m4v[r]) + cqPs;  // = sK1+mv-K2*fe
          p[r] = __builtin_amdgcn_exp2f(fmaf(fminf(fe, 0.f), twoK2, tv));
        }
        lr += (p[0] + p[1]) + (p[2] + p[3]);
        pw[T >> 1][(T & 1) * 2 + 0] = pack_bf2(p[0], p[1]);
        pw[T >> 1][(T & 1) * 2 + 1] = pack_bf2(p[2], p[3]);
      }
    }

    // PV: A = in-register P, B = V from LDS (key order baked into Vt)
#pragma unroll
    for (int kst = 0; kst < 2; kst++) {
      bf16x8 bv[4];
#pragma unroll
      for (int tt = 0; tt < 4; tt++)
        bv[tt] = *(const bf16x8*)(vs + (tt * 16 + l16) * 64 +
                                  ((kst * 4 + quad) ^ sx) * 8);
      union { u32 w[4]; bf16x8 v; } ap;
      ap.w[0] = pw[kst][0]; ap.w[1] = pw[kst][1];
      ap.w[2] = pw[kst][2]; ap.w[3] = pw[kst][3];
#pragma unroll
      for (int tt = 0; tt < 4; tt++)
        accO[tt] = MFMA16(ap.v, bv[tt], accO[tt]);
    }

    __syncthreads();
    buf ^= 1;
  }

  // normalize in-register and store bf16 Ao directly ([B,S,E] layout).
  u16* aob = Ao + ((size_t)(b * 2048 + q0)) * 1024 + h * 64;
  float l = lr;
  l += __shfl_xor(l, 16);
  l += __shfl_xor(l, 32);
  float linv[4];
#pragma unroll
  for (int r = 0; r < 4; r++) linv[r] = 1.0f / __shfl(l, quad * 4 + r);
#pragma unroll
  for (int r = 0; r < 4; r++) {
    u16* arow = aob + (size_t)(quad * 4 + r) * 1024;
#pragma unroll
    for (int tt = 0; tt < 4; tt++)
      arow[tt * 16 + l16] = f2bf(accO[tt][r] * linv[r]);
  }
}

// ---------------------------------------------------------------------------
extern "C" void kernel_launch(void* const* d_in, const int* in_sizes, int n_in,
                              void* d_out, int out_size, void* d_ws, size_t ws_size,
                              hipStream_t stream) {
  const float* x  = (const float*)d_in[0];
  const float* Wq = (const float*)d_in[1];
  const float* Wk = (const float*)d_in[2];
  const float* Wv = (const float*)d_in[3];
  const float* Wo = (const float*)d_in[4];
  const int* mask = (const int*)d_in[5];

  const int M = 4096, N = 1024, K = 1024;
  const int NE = M * N, NW = N * K;
  const int NB = (NE + 4 * NW) / 2048;

  u16* xb    = (u16*)d_ws;
  u16* Wqkvb = xb + NE;
  u16* Wob   = Wqkvb + (size_t)3 * NW;
  u16* Qb    = Wob + NW;
  u16* Kb    = Qb + NE;
  u16* Vt    = Kb + NE;
  u16* Ao    = Vt + NE;
  float* Mbg = (float*)(Ao + NE);            // 4096-key bias table (16 KB)

  cvt_all<<<NB + 1, 256, 0, stream>>>(x, Wq, Wk, Wv, Wo, mask,
                                      xb, Wqkvb, Wob, Mbg, NE, NW, NB);

  gemm_qkv<<<768, 256, 0, stream>>>(xb, Wqkvb, Qb, Kb, Vt, M, 3072, K);
  attn_fwd<<<512, 512, 0, stream>>>(Qb, Kb, Vt, Mbg, Ao);
  gemm_out<<<512, 256, 0, stream>>>(Ao, Wob, (float*)d_out, M, N, K);
}

// Round 9
// 179.763 us; speedup vs baseline: 1.0338x; 1.0338x over previous
//
#include <hip/hip_runtime.h>

typedef unsigned short u16;
typedef unsigned int u32;
typedef unsigned long long u64;
typedef __attribute__((ext_vector_type(8))) short bf16x8;   // 8 bf16 = 4 VGPRs
typedef __attribute__((ext_vector_type(4))) float f32x4;
typedef __attribute__((ext_vector_type(2))) float f32x2;
typedef __attribute__((ext_vector_type(2))) unsigned int u32x2;
typedef __attribute__((ext_vector_type(4))) unsigned int u32x4;

#define MFMA16(A, B, C) __builtin_amdgcn_mfma_f32_16x16x32_bf16(A, B, C, 0, 0, 0)

__device__ __forceinline__ u16 f2bf(float f) {
  union { float f; unsigned u; } x; x.f = f;
  unsigned r = x.u + 0x7fffu + ((x.u >> 16) & 1u);   // RNE
  return (u16)(r >> 16);
}

// pack two fp32 -> two bf16 in one dword via HW cvt_pk (RNE): lo16=a, hi16=b.
__device__ __forceinline__ u32 pack_bf2(float a, float b) {
  u32 r;
  asm("v_cvt_pk_bf16_f32 %0, %1, %2" : "=v"(r) : "v"(a), "v"(b));
  return r;
}

// packed fp32 math (VOP3P, MI200+): d = a*b+c / a+b per 32-bit half
__device__ __forceinline__ f32x2 pk_fma(f32x2 a, f32x2 b, f32x2 c) {
  f32x2 d;
  asm("v_pk_fma_f32 %0, %1, %2, %3" : "=v"(d) : "v"(a), "v"(b), "v"(c));
  return d;
}
__device__ __forceinline__ f32x2 pk_add(f32x2 a, f32x2 b) {
  f32x2 d;
  asm("v_pk_add_f32 %0, %1, %2" : "=v"(d) : "v"(a), "v"(b));
  return d;
}

// async global->LDS, 16B/lane; dest must be wave-uniform base + lane*16
__device__ __forceinline__ void gload_lds16(const u16* g, u16* l) {
  __builtin_amdgcn_global_load_lds((const __attribute__((address_space(1))) void*)g,
                                   (__attribute__((address_space(3))) void*)l,
                                   16, 0, 0);
}

// ---------------------------------------------------------------------------
// fp32 -> bf16 for x, Wq|Wk|Wv (concat -> Wqkvb), Wo; last block builds the
// per-key bias table Mb[key] = K3 + (mask ? -1e6 : 0)  (log2-domain).
// ---------------------------------------------------------------------------
__global__ __launch_bounds__(256) void cvt_all(const float* __restrict__ x,
                                               const float* __restrict__ Wq,
                                               const float* __restrict__ Wk,
                                               const float* __restrict__ Wv,
                                               const float* __restrict__ Wo,
                                               const int* __restrict__ mask,
                                               u16* __restrict__ xb,
                                               u16* __restrict__ Wqkvb,
                                               u16* __restrict__ Wob,
                                               float* __restrict__ Mbg,
                                               int NE, int NW, int NB) {
  if ((int)blockIdx.x == NB) {              // bias-table block: 4096 keys
    const int t = threadIdx.x;
    const int j0 = t * 16;
    const float K3C = -8.0f * 1.44269504f;
    const float KMS = K3C - 1.0e6f;         // exp2 -> exactly 0
#pragma unroll
    for (int jj = 0; jj < 16; jj += 4) {
      const int4 m4 = *(const int4*)(mask + j0 + jj);
      float4 o;
      o.x = m4.x ? KMS : K3C;
      o.y = m4.y ? KMS : K3C;
      o.z = m4.z ? KMS : K3C;
      o.w = m4.w ? KMS : K3C;
      *(float4*)(Mbg + j0 + jj) = o;
    }
    return;
  }
  const int e = (blockIdx.x * 256 + threadIdx.x) * 8;
  const float* s;
  u16* d;
  if (e < NE) { s = x + e; d = xb + e; }
  else {
    int f = e - NE;
    if (f < 3 * NW) {
      d = Wqkvb + f;
      s = (f < NW) ? Wq + f : (f < 2 * NW) ? Wk + (f - NW) : Wv + (f - 2 * NW);
    } else { f -= 3 * NW; s = Wo + f; d = Wob + f; }
  }
  const float4 a = *(const float4*)s;
  const float4 b = *(const float4*)(s + 4);
  bf16x8 o;
  o[0] = (short)f2bf(a.x); o[1] = (short)f2bf(a.y);
  o[2] = (short)f2bf(a.z); o[3] = (short)f2bf(a.w);
  o[4] = (short)f2bf(b.x); o[5] = (short)f2bf(b.y);
  o[6] = (short)f2bf(b.z); o[7] = (short)f2bf(b.w);
  *(bf16x8*)d = o;
}

// ---------------------------------------------------------------------------
// Fused QKV NT GEMM: [4096,1024] @ [3072,1024]^T. 128x128 tile, BK=64,
// global_load_lds x16 staging, XOR-chunk swizzle, XCD-chunked block order.
// V -> per-head-transposed Vt with key interleave matching attn's in-register
// P fragments: p = r + 4*(T&1) + 8*quad + 32*(T>>1) for key k = T*16+quad*4+r.
// ---------------------------------------------------------------------------
__global__ __launch_bounds__(256) void gemm_qkv(const u16* __restrict__ A,
                                                const u16* __restrict__ B,
                                                u16* __restrict__ Qo,
                                                u16* __restrict__ Ko,
                                                u16* __restrict__ Vto,
                                                int M, int N, int K) {
  __shared__ alignas(16) u16 As[128 * 64];   // 16 KB, chunk-linear + XOR col
  __shared__ alignas(16) u16 Bs[128 * 64];   // 16 KB
  const int t = threadIdx.x;
  const int lane = t & 63, wave = t >> 6;
  const int quad = lane >> 4, l16 = lane & 15;
  // XCD-chunked swizzle: 768 blocks = 8 XCDs x 96 (bijective).
  const int bid = blockIdx.x;
  const int swz = (bid & 7) * 96 + (bid >> 3);
  const int m0 = (swz / 24) * 128, n0 = (swz % 24) * 128;
  const int wm = (wave >> 1) * 64, wn = (wave & 1) * 64;
  const int sx = l16 & 7;

  f32x4 acc[4][4] = {};

  for (int kk = 0; kk < K; kk += 64) {
#pragma unroll
    for (int i = 0; i < 4; i++) {
      const int c = t + i * 256;              // chunk id in [0,1024)
      const int row = c >> 3, sub = c & 7;
      const int col = ((sub ^ (row & 7)) * 8);
      gload_lds16(A + (size_t)(m0 + row) * K + kk + col, As + (size_t)c * 8);
      gload_lds16(B + (size_t)(n0 + row) * K + kk + col, Bs + (size_t)c * 8);
    }
    __syncthreads();

#pragma unroll
    for (int ks = 0; ks < 2; ks++) {
      bf16x8 af[4], bfr[4];
#pragma unroll
      for (int i = 0; i < 4; i++)
        af[i] = *(const bf16x8*)(As + (wm + i * 16 + l16) * 64 +
                                 ((ks * 4 + quad) ^ sx) * 8);
#pragma unroll
      for (int j = 0; j < 4; j++)
        bfr[j] = *(const bf16x8*)(Bs + (wn + j * 16 + l16) * 64 +
                                  ((ks * 4 + quad) ^ sx) * 8);
#pragma unroll
      for (int i = 0; i < 4; i++)
#pragma unroll
        for (int j = 0; j < 4; j++)
          acc[i][j] = MFMA16(af[i], bfr[j], acc[i][j]);
    }
    __syncthreads();
  }

  const int G = ((m0 + wm) & 2047) >> 6;
#pragma unroll
  for (int j = 0; j < 4; j++) {
    const int col = n0 + wn + j * 16 + l16;
    if (col < 1024) {
#pragma unroll
      for (int i = 0; i < 4; i++)
#pragma unroll
        for (int r = 0; r < 4; r++)
          Qo[(size_t)(m0 + wm + i * 16 + quad * 4 + r) * 1024 + col] =
              f2bf(acc[i][j][r]);
    } else if (col < 2048) {
#pragma unroll
      for (int i = 0; i < 4; i++)
#pragma unroll
        for (int r = 0; r < 4; r++)
          Ko[(size_t)(m0 + wm + i * 16 + quad * 4 + r) * 1024 + (col - 1024)] =
              f2bf(acc[i][j][r]);
    } else {
      u16* base = Vto + ((size_t)(m0 >> 11) * 1024 + (col - 2048)) * 2048 + G * 64;
      const int C = 8 * (quad & 1) + 16 * (quad >> 1);
      u32x4 w0, w1;
      w0.x = pack_bf2(acc[0][j][0], acc[0][j][1]);
      w0.y = pack_bf2(acc[0][j][2], acc[0][j][3]);
      w0.z = pack_bf2(acc[1][j][0], acc[1][j][1]);
      w0.w = pack_bf2(acc[1][j][2], acc[1][j][3]);
      w1.x = pack_bf2(acc[2][j][0], acc[2][j][1]);
      w1.y = pack_bf2(acc[2][j][2], acc[2][j][3]);
      w1.z = pack_bf2(acc[3][j][0], acc[3][j][1]);
      w1.w = pack_bf2(acc[3][j][2], acc[3][j][3]);
      *(u32x4*)(base + C) = w0;
      *(u32x4*)(base + C + 32) = w1;
    }
  }
}

// ---------------------------------------------------------------------------
// Out GEMM (unfused, DMA-staged): C[4096,1024] fp32 = Ao @ Wo^T.
// ---------------------------------------------------------------------------
__global__ __launch_bounds__(256) void gemm_out(const u16* __restrict__ A,
                                                const u16* __restrict__ B,
                                                float* __restrict__ C,
                                                int M, int N, int K) {
  __shared__ alignas(16) u16 As[128 * 64];   // 16 KB
  __shared__ alignas(16) u16 Bs[64 * 64];    // 8 KB
  const int t = threadIdx.x;
  const int lane = t & 63, wave = t >> 6;
  const int quad = lane >> 4, l16 = lane & 15;
  // XCD-chunked swizzle: 512 blocks = 8 x 64 (bijective).
  const int bid = blockIdx.x;
  const int swz = (bid & 7) * 64 + (bid >> 3);
  const int m0 = (swz >> 4) * 128, n0 = (swz & 15) * 64;
  const int wm = (wave >> 1) * 64, wn = (wave & 1) * 32;
  const int sx = l16 & 7;

  f32x4 acc[4][2] = {};

  for (int kk = 0; kk < K; kk += 64) {
#pragma unroll
    for (int i = 0; i < 4; i++) {
      const int c = t + i * 256;              // A chunks [0,1024)
      const int row = c >> 3, sub = c & 7;
      gload_lds16(A + (size_t)(m0 + row) * K + kk + ((sub ^ (row & 7)) * 8),
                  As + (size_t)c * 8);
    }
#pragma unroll
    for (int i = 0; i < 2; i++) {
      const int c = t + i * 256;              // B chunks [0,512)
      const int row = c >> 3, sub = c & 7;
      gload_lds16(B + (size_t)(n0 + row) * K + kk + ((sub ^ (row & 7)) * 8),
                  Bs + (size_t)c * 8);
    }
    __syncthreads();

#pragma unroll
    for (int ks = 0; ks < 2; ks++) {
      bf16x8 af[4], bfr[2];
#pragma unroll
      for (int i = 0; i < 4; i++)
        af[i] = *(const bf16x8*)(As + (wm + i * 16 + l16) * 64 +
                                 ((ks * 4 + quad) ^ sx) * 8);
#pragma unroll
      for (int j = 0; j < 2; j++)
        bfr[j] = *(const bf16x8*)(Bs + (wn + j * 16 + l16) * 64 +
                                  ((ks * 4 + quad) ^ sx) * 8);
#pragma unroll
      for (int i = 0; i < 4; i++)
#pragma unroll
        for (int j = 0; j < 2; j++)
          acc[i][j] = MFMA16(af[i], bfr[j], acc[i][j]);
    }
    __syncthreads();
  }

#pragma unroll
  for (int i = 0; i < 4; i++)
#pragma unroll
    for (int j = 0; j < 2; j++)
#pragma unroll
      for (int r = 0; r < 4; r++)
        C[(size_t)(m0 + wm + i * 16 + quad * 4 + r) * N + n0 + wn + j * 16 + l16] =
            acc[i][j][r];
}

// ---------------------------------------------------------------------------
// Flash attention v14: pair-tile epochs. 128 keys per barrier epoch as two
// 64-key sub-tiles A/B; per-64-key math identical to the verified v13
// (sign-split tables + pk-math fast path, straddle correction per sub-tile).
// SM(B) is register-independent of PV(A) -> compiler interleaves softmax
// VALU with PV MFMAs within one wave; barriers halve (16 epochs).
// LDS 80 KB (K/V pair dbuf 64 KB + tables 16 KB) -> still 2 blocks/CU.
// ---------------------------------------------------------------------------
__global__ __launch_bounds__(512) void attn_fwd(const u16* __restrict__ Q,
                                                const u16* __restrict__ Kb_,
                                                const u16* __restrict__ Vt,
                                                const float* __restrict__ Mb,
                                                u16* __restrict__ Ao) {
  constexpr int S = 2048, E = 1024;
  __shared__ alignas(16) u16 Ks[2][2][64 * 64];  // 32 KB (dbuf x subtile)
  __shared__ alignas(16) u16 Vs[2][2][64 * 64];  // 32 KB
  __shared__ alignas(16) float Msp[2048];        // 8 KB: Mb - K2*(k-2047)
  __shared__ alignas(16) float Msm[2048];        // 8 KB: Mb + K2*(k-2047)
  const int t = threadIdx.x;
  const int lane = t & 63, wave = t >> 6;      // 8 waves
  const int quad = lane >> 4, l16 = lane & 15;
  // XCD-chunked swizzle: 512 blocks = 8 x 64 (bijective).
  const int bid = blockIdx.x;
  const int swz = (bid & 7) * 64 + (bid >> 3);
  const int xq = swz & 15, bh = swz >> 4;
  const int b = bh >> 4, h = bh & 15;
  const int q0 = xq * 128 + wave * 16;         // 16 q-rows per wave

  const int kr0 = t >> 3;                      // chunk t in [0,512)
  const int kcol0 = ((t & 7) ^ (kr0 & 7)) * 8;
  const u16* kP0 = Kb_ + (size_t)(b * S + kr0) * E + h * 64 + kcol0;
  const u16* vbase = Vt + (size_t)(b * 16 + h) * 64 * S;
  const u16* vP0 = vbase + (size_t)kr0 * S + kcol0;

  bf16x8 aq[2];                        // Q fragments (B-operand after swap)
  {
    const u16* qp = Q + ((size_t)(b * S) + q0 + l16) * E + h * 64;
    aq[0] = *(const bf16x8*)(qp + quad * 8);
    aq[1] = *(const bf16x8*)(qp + 32 + quad * 8);
  }

  const int sx = l16 & 7;
  const float K1 = 0.125f * 1.44269504f;
  const float K2 = 2.44140625e-4f * 1.44269504f;

  float lr = 0.f;
  f32x4 accO[4] = {};

  // stage epoch 0 (both sub-tiles)
  gload_lds16(kP0, Ks[0][0] + t * 8);
  gload_lds16(kP0 + (size_t)64 * E, Ks[0][1] + t * 8);
  gload_lds16(vP0, Vs[0][0] + t * 8);
  gload_lds16(vP0 + 64, Vs[0][1] + t * 8);
  // build sign-split bias tables (overlaps with K/V DMA)
  {
    const float4 m4 = *(const float4*)(Mb + b * 2048 + t * 4);
    const float kb = (float)(t * 4) - 2047.0f;
    float4 pp, mm;
    pp.x = fmaf(-K2, kb,       m4.x);  mm.x = fmaf(K2, kb,       m4.x);
    pp.y = fmaf(-K2, kb + 1.f, m4.y);  mm.y = fmaf(K2, kb + 1.f, m4.y);
    pp.z = fmaf(-K2, kb + 2.f, m4.z);  mm.z = fmaf(K2, kb + 2.f, m4.z);
    pp.w = fmaf(-K2, kb + 3.f, m4.w);  mm.w = fmaf(K2, kb + 3.f, m4.w);
    *(float4*)(Msp + t * 4) = pp;
    *(float4*)(Msm + t * 4) = mm;
  }
  __syncthreads();

  const float qn = (float)(q0 + l16);
  const float cqPs = -K2 * qn, cqMs = K2 * qn;
  const f32x2 K1p = {K1, K1};
  const f32x2 cqPp = {cqPs, cqPs}, cqMp = {cqMs, cqMs};
  const float fb0 = (float)(quad * 4 + q0 + l16 - 2047);
  const float twoK2 = 2.0f * K2;

  int buf = 0;
  for (int ke = 0; ke < 2048; ke += 128) {
    if (ke + 128 < 2048) {
      const int kn = ke + 128;
      gload_lds16(kP0 + (size_t)kn * E, Ks[buf ^ 1][0] + t * 8);
      gload_lds16(kP0 + (size_t)(kn + 64) * E, Ks[buf ^ 1][1] + t * 8);
      gload_lds16(vP0 + kn, Vs[buf ^ 1][0] + t * 8);
      gload_lds16(vP0 + kn + 64, Vs[buf ^ 1][1] + t * 8);
    }

    // ---- QK^T for both sub-tiles ----
    f32x4 sA[4] = {}, sB[4] = {};
    {
      const u16* ksA = Ks[buf][0];
#pragma unroll
      for (int T = 0; T < 4; T++) {
        bf16x8 b0 = *(const bf16x8*)(ksA + (T * 16 + l16) * 64 +
                                     ((0 + quad) ^ sx) * 8);
        bf16x8 b1 = *(const bf16x8*)(ksA + (T * 16 + l16) * 64 +
                                     ((4 + quad) ^ sx) * 8);
        sA[T] = MFMA16(b0, aq[0], sA[T]);
        sA[T] = MFMA16(b1, aq[1], sA[T]);
      }
      const u16* ksB = Ks[buf][1];
#pragma unroll
      for (int T = 0; T < 4; T++) {
        bf16x8 b0 = *(const bf16x8*)(ksB + (T * 16 + l16) * 64 +
                                     ((0 + quad) ^ sx) * 8);
        bf16x8 b1 = *(const bf16x8*)(ksB + (T * 16 + l16) * 64 +
                                     ((4 + quad) ^ sx) * 8);
        sB[T] = MFMA16(b0, aq[0], sB[T]);
        sB[T] = MFMA16(b1, aq[1], sB[T]);
      }
    }

    // ---- sub-tile A: softmax + PV ----
    u32 pwA[2][4];
    {
      const int kq = ke + q0;
      if (kq >= 2047 || kq <= 1969) {   // uniform-sign fast path
        const float* mst = (kq >= 2047) ? Msp : Msm;
        const f32x2 cqp = (kq >= 2047) ? cqPp : cqMp;
#pragma unroll
        for (int T = 0; T < 4; T++) {
          const f32x4 m4v = *(const f32x4*)(mst + ke + 16 * T + quad * 4);
          const f32x2 s01 = {sA[T][0], sA[T][1]}, s23 = {sA[T][2], sA[T][3]};
          const f32x2 m01 = {m4v[0], m4v[1]}, m23 = {m4v[2], m4v[3]};
          const f32x2 a01 = pk_add(pk_fma(s01, K1p, m01), cqp);
          const f32x2 a23 = pk_add(pk_fma(s23, K1p, m23), cqp);
          const float p0 = __builtin_amdgcn_exp2f(a01[0]);
          const float p1 = __builtin_amdgcn_exp2f(a01[1]);
          const float p2 = __builtin_amdgcn_exp2f(a23[0]);
          const float p3 = __builtin_amdgcn_exp2f(a23[1]);
          lr += (p0 + p1) + (p2 + p3);
          pwA[T >> 1][(T & 1) * 2 + 0] = pack_bf2(p0, p1);
          pwA[T >> 1][(T & 1) * 2 + 1] = pack_bf2(p2, p3);
        }
      } else {                          // straddle: exact correction
        const float fbLk = fb0 + (float)ke;
#pragma unroll
        for (int T = 0; T < 4; T++) {
          const f32x4 m4v = *(const f32x4*)(Msp + ke + 16 * T + quad * 4);
          float p[4];
#pragma unroll
          for (int r = 0; r < 4; r++) {
            const float fe = fbLk + (float)(16 * T + r);
            const float tv = fmaf(sA[T][r], K1, m4v[r]) + cqPs;
            p[r] = __builtin_amdgcn_exp2f(fmaf(fminf(fe, 0.f), twoK2, tv));
          }
          lr += (p[0] + p[1]) + (p[2] + p[3]);
          pwA[T >> 1][(T & 1) * 2 + 0] = pack_bf2(p[0], p[1]);
          pwA[T >> 1][(T & 1) * 2 + 1] = pack_bf2(p[2], p[3]);
        }
      }
    }
    {
      const u16* vsA = Vs[buf][0];
#pragma unroll
      for (int kst = 0; kst < 2; kst++) {
        bf16x8 bv[4];
#pragma unroll
        for (int tt = 0; tt < 4; tt++)
          bv[tt] = *(const bf16x8*)(vsA + (tt * 16 + l16) * 64 +
                                    ((kst * 4 + quad) ^ sx) * 8);
        union { u32 w[4]; bf16x8 v; } ap;
        ap.w[0] = pwA[kst][0]; ap.w[1] = pwA[kst][1];
        ap.w[2] = pwA[kst][2]; ap.w[3] = pwA[kst][3];
#pragma unroll
        for (int tt = 0; tt < 4; tt++)
          accO[tt] = MFMA16(ap.v, bv[tt], accO[tt]);
      }
    }

    // ---- sub-tile B: softmax + PV (independent of PV A -> overlaps) ----
    u32 pwB[2][4];
    {
      const int keB = ke + 64;
      const int kq = keB + q0;
      if (kq >= 2047 || kq <= 1969) {
        const float* mst = (kq >= 2047) ? Msp : Msm;
        const f32x2 cqp = (kq >= 2047) ? cqPp : cqMp;
#pragma unroll
        for (int T = 0; T < 4; T++) {
          const f32x4 m4v = *(const f32x4*)(mst + keB + 16 * T + quad * 4);
          const f32x2 s01 = {sB[T][0], sB[T][1]}, s23 = {sB[T][2], sB[T][3]};
          const f32x2 m01 = {m4v[0], m4v[1]}, m23 = {m4v[2], m4v[3]};
          const f32x2 a01 = pk_add(pk_fma(s01, K1p, m01), cqp);
          const f32x2 a23 = pk_add(pk_fma(s23, K1p, m23), cqp);
          const float p0 = __builtin_amdgcn_exp2f(a01[0]);
          const float p1 = __builtin_amdgcn_exp2f(a01[1]);
          const float p2 = __builtin_amdgcn_exp2f(a23[0]);
          const float p3 = __builtin_amdgcn_exp2f(a23[1]);
          lr += (p0 + p1) + (p2 + p3);
          pwB[T >> 1][(T & 1) * 2 + 0] = pack_bf2(p0, p1);
          pwB[T >> 1][(T & 1) * 2 + 1] = pack_bf2(p2, p3);
        }
      } else {
        const float fbLk = fb0 + (float)keB;
#pragma unroll
        for (int T = 0; T < 4; T++) {
          const f32x4 m4v = *(const f32x4*)(Msp + keB + 16 * T + quad * 4);
          float p[4];
#pragma unroll
          for (int r = 0; r < 4; r++) {
            const float fe = fbLk + (float)(16 * T + r);
            const float tv = fmaf(sB[T][r], K1, m4v[r]) + cqPs;
            p[r] = __builtin_amdgcn_exp2f(fmaf(fminf(fe, 0.f), twoK2, tv));
          }
          lr += (p[0] + p[1]) + (p[2] + p[3]);
          pwB[T >> 1][(T & 1) * 2 + 0] = pack_bf2(p[0], p[1]);
          pwB[T >> 1][(T & 1) * 2 + 1] = pack_bf2(p[2], p[3]);
        }
      }
    }
    {
      const u16* vsB = Vs[buf][1];
#pragma unroll
      for (int kst = 0; kst < 2; kst++) {
        bf16x8 bv[4];
#pragma unroll
        for (int tt = 0; tt < 4; tt++)
          bv[tt] = *(const bf16x8*)(vsB + (tt * 16 + l16) * 64 +
                                    ((kst * 4 + quad) ^ sx) * 8);
        union { u32 w[4]; bf16x8 v; } ap;
        ap.w[0] = pwB[kst][0]; ap.w[1] = pwB[kst][1];
        ap.w[2] = pwB[kst][2]; ap.w[3] = pwB[kst][3];
#pragma unroll
        for (int tt = 0; tt < 4; tt++)
          accO[tt] = MFMA16(ap.v, bv[tt], accO[tt]);
      }
    }

    __syncthreads();
    buf ^= 1;
  }

  // normalize in-register and store bf16 Ao directly ([B,S,E] layout).
  u16* aob = Ao + ((size_t)(b * 2048 + q0)) * 1024 + h * 64;
  float l = lr;
  l += __shfl_xor(l, 16);
  l += __shfl_xor(l, 32);
  float linv[4];
#pragma unroll
  for (int r = 0; r < 4; r++) linv[r] = 1.0f / __shfl(l, quad * 4 + r);
#pragma unroll
  for (int r = 0; r < 4; r++) {
    u16* arow = aob + (size_t)(quad * 4 + r) * 1024;
#pragma unroll
    for (int tt = 0; tt < 4; tt++)
      arow[tt * 16 + l16] = f2bf(accO[tt][r] * linv[r]);
  }
}

// ---------------------------------------------------------------------------
extern "C" void kernel_launch(void* const* d_in, const int* in_sizes, int n_in,
                              void* d_out, int out_size, void* d_ws, size_t ws_size,
                              hipStream_t stream) {
  const float* x  = (const float*)d_in[0];
  const float* Wq = (const float*)d_in[1];
  const float* Wk = (const float*)d_in[2];
  const float* Wv = (const float*)d_in[3];
  const float* Wo = (const float*)d_in[4];
  const int* mask = (const int*)d_in[5];

  const int M = 4096, N = 1024, K = 1024;
  const int NE = M * N, NW = N * K;
  const int NB = (NE + 4 * NW) / 2048;

  u16* xb    = (u16*)d_ws;
  u16* Wqkvb = xb + NE;
  u16* Wob   = Wqkvb + (size_t)3 * NW;
  u16* Qb    = Wob + NW;
  u16* Kb    = Qb + NE;
  u16* Vt    = Kb + NE;
  u16* Ao    = Vt + NE;
  float* Mbg = (float*)(Ao + NE);            // 4096-key bias table (16 KB)

  cvt_all<<<NB + 1, 256, 0, stream>>>(x, Wq, Wk, Wv, Wo, mask,
                                      xb, Wqkvb, Wob, Mbg, NE, NW, NB);

  gemm_qkv<<<768, 256, 0, stream>>>(xb, Wqkvb, Qb, Kb, Vt, M, 3072, K);
  attn_fwd<<<512, 512, 0, stream>>>(Qb, Kb, Vt, Mbg, Ao);
  gemm_out<<<512, 256, 0, stream>>>(Ao, Wob, (float*)d_out, M, N, K);
}